// Round 1
// baseline (194.775 us; speedup 1.0000x reference)
//
#include <hip/hip_runtime.h>

// DilateAttention: B=4, d=384 (12 heads x 32), H=W=64, 3x3 taps, dilation 2, pad 2.
// f32 in / f32 out.
// v2: latency-bound fix — split the 32 head channels across 4 lane-groups
// (8 ch/thread) => 4x wave count (12288 waves, 12/SIMD available), 4x fewer
// loads per wave. Cross-group QK reduce via __shfl_xor(16/32) in-wave.
// 32-bit index addressing (uniform SGPR base + VGPR offset) to cut VGPR/VALU.
// XCD-chunked block swizzle for y-adjacent k/v row reuse in per-XCD L2.

#define NHD  12
#define DDIM 384
#define HH   64
#define WW   64
#define HWSZ 4096
#define SCALEF 0.17677669529663687f  // 1/sqrt(32)

// block = 256 = 4 waves; each wave: 16 pixels x 4 channel-groups.
// lane = (cg<<4)|xl  -> the 4 partials for one pixel sit in lanes xl, xl+16,
// xl+32, xl+48 of the SAME wave (shuffle-reducible).
// grid = B*NH*H = 3072 blocks (one row of 64 px per block).
__global__ __launch_bounds__(256, 6) void dilate_attn(const float* __restrict__ q,
                                                      const float* __restrict__ k,
                                                      const float* __restrict__ v,
                                                      float* __restrict__ out) {
    const int tid = threadIdx.x;
    const int xl  = tid & 15;           // pixel within wave
    const int cg  = (tid >> 4) & 3;     // channel group (8 ch each)
    const int x   = ((tid >> 6) << 4) | xl;   // global x 0..63

    // XCD-chunked swizzle: 3072 blocks = 8 XCDs x 384 contiguous (bijective).
    int bz = blockIdx.x;
    bz = (bz & 7) * 384 + (bz >> 3);

    const int y  = bz & 63;
    const int bh = bz >> 6;             // b*NH + n
    const int b  = bh / NHD;
    const int n  = bh - b * NHD;

    // 32-bit element index base (max ~6.3M elements, fits easily).
    const int cbase = (b * DDIM + n * 32 + cg * 8) * HWSZ;
    const int pix   = y * WW + x;

    // 9 tap offsets, clamped to center when OOB; validity recorded separately.
    int  toff[9];
    bool tval[9];
#pragma unroll
    for (int di = 0; di < 3; ++di) {
        int yy = y + 2 * di - 2;
        bool vy = (yy >= 0) && (yy < HH);
#pragma unroll
        for (int p = 0; p < 3; ++p) {
            int xo = x + 2 * p - 2;
            bool ok = vy && (xo >= 0) && (xo < WW);
            tval[di * 3 + p] = ok;
            toff[di * 3 + p] = ok ? (yy * WW + xo) : pix;  // clamped: in-bounds
        }
    }

    // ---------------- preload q (scale folded in): 8 channels ----------------
    float qreg[8];
#pragma unroll
    for (int c = 0; c < 8; ++c) qreg[c] = q[cbase + pix + c * HWSZ] * SCALEF;

    // ---------------- Phase 1: 9 partial logits over 8 channels --------------
    float l[9];
#pragma unroll
    for (int t = 0; t < 9; ++t) {
        const int kb = cbase + toff[t];
        float a0 = 0.f, a1 = 0.f;
#pragma unroll
        for (int c = 0; c < 8; c += 2) {
            a0 += qreg[c]     * k[kb + c * HWSZ];
            a1 += qreg[c + 1] * k[kb + (c + 1) * HWSZ];
        }
        l[t] = tval[t] ? (a0 + a1) : 0.f;  // zero-pad taps contribute logit 0
    }

    // ---- butterfly reduce across the 4 channel groups (lane bits 4,5) ------
#pragma unroll
    for (int t = 0; t < 9; ++t) {
        l[t] += __shfl_xor(l[t], 16, 64);
        l[t] += __shfl_xor(l[t], 32, 64);
    }

    // ---------------- Softmax over 9 (redundant in each group, cheap) -------
    float m = l[0];
#pragma unroll
    for (int t = 1; t < 9; ++t) m = fmaxf(m, l[t]);
    float w[9], s = 0.f;
#pragma unroll
    for (int t = 0; t < 9; ++t) { w[t] = __expf(l[t] - m); s += w[t]; }
    float inv = 1.0f / s;
#pragma unroll
    for (int t = 0; t < 9; ++t) w[t] = tval[t] ? (w[t] * inv) : 0.f;  // padded V == 0

    // ---------------- Phase 2: weighted V over this group's 8 channels ------
    float o[8];
#pragma unroll
    for (int c = 0; c < 8; ++c) o[c] = 0.f;
#pragma unroll
    for (int t = 0; t < 9; ++t) {
        const int vb = cbase + toff[t];
        float wt = w[t];
#pragma unroll
        for (int c = 0; c < 8; ++c) o[c] += wt * v[vb + c * HWSZ];
    }

    // out[b, y, x, n*32 + cg*8 .. +8): 32-B aligned, two float4 stores.
    // Groups 0..3 of one pixel sit in one wave -> contiguous 128 B per pixel.
    const int ob = ((b * HH + y) * WW + x) * DDIM + n * 32 + cg * 8;
    *(float4*)(out + ob)     = make_float4(o[0], o[1], o[2], o[3]);
    *(float4*)(out + ob + 4) = make_float4(o[4], o[5], o[6], o[7]);
}

extern "C" void kernel_launch(void* const* d_in, const int* in_sizes, int n_in,
                              void* d_out, int out_size, void* d_ws, size_t ws_size,
                              hipStream_t stream) {
    const float* q = (const float*)d_in[0];
    const float* k = (const float*)d_in[1];
    const float* v = (const float*)d_in[2];
    float* out = (float*)d_out;
    hipLaunchKernelGGL(dilate_attn, dim3(3072), dim3(256), 0, stream, q, k, v, out);
}